// Round 12
// baseline (8183.514 us; speedup 1.0000x reference)
//
#include <hip/hip_runtime.h>
#include <cmath>

namespace {
constexpr int Hc = 8, FFc = 512, HIDc = 512;
}

struct Params {
  const float *coords, *Wi, *bi, *W_ph;
  const float *Wq, *Wk, *Wv, *Wo, *g1, *b1, *fW1, *fb1, *fW2, *fb2, *g2, *b2;
  const float *W_node, *W_fixed, *W_step, *W_out, *Wc1, *bc1, *Wc2, *bc2;
  float* out;
};

// Journal: R7 structure (6.91 ms anchor) with ka1+ka2 merged into per-sample `ka`:
// QKV weight traffic 393->~100 MB/dispatch (col-ordered pack, distinct cols per wave-instr),
// g_h round-trip eliminated, 1 launch/layer saved. kff/kd1/kd2 untouched (R7-exact).
__device__ __align__(16) float g_bn[120 * 8 * 256]; // BN stats, 8-way replicated
__device__ __align__(16) float g_x[512 * 2560];
__device__ __align__(16) float g_t[512 * 2560];
__device__ __align__(16) float g_dec[512 * 7680];   // gK|gV|lK per sample: [i<20][j<384]
__device__ __align__(16) float g_qv[512 * 128];
__device__ float g_val[512];
__device__ __align__(16) float g_crd[512 * 40];
__device__ int   g_idx[512 * 20];
__device__ float g_state[512 * 8];
__device__ __align__(16) float g_ctxq[128];
__device__ __align__(16) float g_cctx[512];
// Packed weights (coalesced)
__device__ __align__(16) float g_Wqkvp[3 * 49152];  // [l][d4<32][col<384][4]: col 0-127=q,128-255=k,256-383=v
__device__ __align__(16) float g_Wop[3 * 16384];    // [l][c4<32][j<128][4]
__device__ __align__(16) float g_W1q[3 * 65536];    // [l][k4<32][c<8][cg<64][4]: col=cg*8+c
__device__ __align__(16) float g_W2q[3 * 65536];    // [l][k4<128][c<4][cg<32][4]: col=cg*4+c
__device__ __align__(16) float g_Wnp[49152];        // [e4<32][col<384][4]
__device__ __align__(16) float g_Wfp[16384];        // [e4<32][j<128][4]
__device__ __align__(16) float g_Woup[16384];       // [c4<32][j<128][4]
__device__ __align__(16) float g_Wc1p[65536];       // [e4<32][jj<512][4]

#define DOT4(a, b) ((a).x*(b).x + (a).y*(b).y + (a).z*(b).z + (a).w*(b).w)

__device__ __forceinline__ void bn_coef(int slot, const float* g, const float* bb, float cnt,
                                        float* s_scale, float* s_shift, int tid) {
  if (tid < 128) {
    float sm = 0.f, sq = 0.f;
#pragma unroll
    for (int r = 0; r < 8; r++) {
      const float* s = &g_bn[(slot * 8 + r) * 256];
      sm += s[tid]; sq += s[128 + tid];
    }
    float m_ = sm / cnt;
    float v_ = sq / cnt - m_ * m_;
    float rs = rsqrtf(v_ + 1e-5f);
    float sc = rs * g[tid];
    s_scale[tid] = sc;
    s_shift[tid] = bb[tid] - m_ * sc;
  }
}

__global__ __launch_bounds__(256) void kinit(Params p) {
  const int tid = threadIdx.x, b = blockIdx.x;
  const int gid = b * 256 + tid, GS = 512 * 256;
  for (int i = gid; i < 120 * 8 * 256; i += GS) g_bn[i] = 0.f;
  if (gid < 512) g_val[gid] = 0.f;
  for (int e = tid; e < 2560; e += 256) {
    int i = e >> 7, d = e & 127;
    float cx = p.coords[b * 40 + 2 * i], cy = p.coords[b * 40 + 2 * i + 1];
    g_x[b * 2560 + e] = cx * p.Wi[d] + cy * p.Wi[128 + d] + p.bi[d];
  }
  if (tid < 40) g_crd[b * 40 + tid] = p.coords[b * 40 + tid];
  if (tid < 20) g_idx[b * 20 + tid] = tid;
  if (tid < 8) g_state[b * 8 + tid] = 0.f;
  if (b == 0) {
    if (tid < 128) {
      float a = 0.f;
      for (int j = 0; j < 256; j++) a += p.W_ph[j] * p.W_step[j * 128 + tid];
      g_ctxq[tid] = a;
    }
    for (int jj = tid; jj < 512; jj += 256) {
      float a = p.bc1[jj];
      for (int e = 0; e < 256; e++) a += p.W_ph[e] * p.Wc1[(128 + e) * 512 + jj];
      g_cctx[jj] = a;
    }
  }
  // QKV pack, col-ordered: e = ((l*32 + d4)*384 + col)*4 + sub
  for (int e = gid; e < 3 * 49152; e += GS) {
    int sub = e & 3, q = e >> 2;
    int col = q % 384, q2 = q / 384, d4 = q2 & 31, l = q2 >> 5;
    int d = d4 * 4 + sub;
    float v;
    if (col < 128)      v = p.Wq[l * 16384 + (col >> 4) * 2048 + d * 16 + (col & 15)];
    else if (col < 256) { int j = col - 128; v = p.Wk[l * 16384 + (j >> 4) * 2048 + d * 16 + (j & 15)]; }
    else                { int j = col - 256; v = p.Wv[l * 16384 + (j >> 4) * 2048 + d * 16 + (j & 15)]; }
    g_Wqkvp[e] = v;
  }
  for (int e = gid; e < 3 * 16384; e += GS) {
    int sub = e & 3, rest = e >> 2;
    int j = rest & 127, rest2 = rest >> 7, c4 = rest2 & 31, l = rest2 >> 5;
    int c = c4 * 4 + sub;
    g_Wop[e] = p.Wo[l * 16384 + (c >> 4) * 2048 + (c & 15) * 128 + j];
  }
  // kff packs
  for (int e = gid; e < 3 * 65536; e += GS) {
    int sub = e & 3, f = (e >> 2) & 16383, l = e >> 16;
    int cg = f & 63, c = (f >> 6) & 7, k4 = f >> 9;        // k4<32
    g_W1q[e] = p.fW1[l * 65536 + (k4 * 4 + sub) * 512 + cg * 8 + c];
  }
  for (int e = gid; e < 3 * 65536; e += GS) {
    int sub = e & 3, f = (e >> 2) & 16383, l = e >> 16;
    int cg = f & 31, c = (f >> 5) & 3, k4 = f >> 7;        // k4<128
    g_W2q[e] = p.fW2[l * 65536 + (k4 * 4 + sub) * 128 + cg * 4 + c];
  }
  for (int e = gid; e < 49152; e += GS) {
    int sub = e & 3, rest = e >> 2;
    int col = rest % 384, e4 = rest / 384;
    g_Wnp[e] = p.W_node[(e4 * 4 + sub) * 384 + col];
  }
  for (int e = gid; e < 16384; e += GS) {
    int sub = e & 3, rest = e >> 2;
    int j = rest & 127, e4 = rest >> 7;
    g_Wfp[e] = p.W_fixed[(e4 * 4 + sub) * 128 + j];
    g_Woup[e] = p.W_out[(e4 * 4 + sub) * 128 + j];
  }
  for (int e = gid; e < 65536; e += GS) {
    int sub = e & 3, rest = e >> 2;
    int jj = rest & 511, e4 = rest >> 9;
    g_Wc1p[e] = p.Wc1[(e4 * 4 + sub) * 512 + jj];
  }
}

// KA: grid 512 (per sample). [BN2(l-1) apply] -> QKV (all heads) -> softmax -> AV (h in LDS)
// -> out-proj + residual -> g_t, BN1 stats. Replaces ka1+ka2.
__global__ __launch_bounds__(256) void ka(Params p, int step, int l) {
  const int tid = threadIdx.x, b = blockIdx.x;
  const int n = 20 - step;
  __shared__ __align__(16) float s_x[2560];
  __shared__ __align__(16) float s_q[2560];       // q, later h (AV output)
  __shared__ float s_kT[2560];                     // [kcol<128][20]
  __shared__ __align__(16) float s_v[2560];
  __shared__ float s_att[3200];                    // [8][20][20]
  __shared__ __align__(16) float s_scale[128], s_shift[128];
  __shared__ float s_sm[128], s_sq[128];

  if (l > 0)
    bn_coef(step * 6 + (l - 1) * 2 + 1, p.g2 + (l - 1) * 128, p.b2 + (l - 1) * 128,
            (float)(512 * n), s_scale, s_shift, tid);
  __syncthreads();
  const float4* src4 = (const float4*)((l == 0 ? g_x : g_t) + b * 2560);
  float4* st4 = (float4*)s_x;
  for (int e4 = tid; e4 < n * 32; e4 += 256) {
    float4 x = src4[e4];
    if (l > 0) {
      float4 sc = ((const float4*)s_scale)[e4 & 31];
      float4 sh = ((const float4*)s_shift)[e4 & 31];
      x.x = x.x * sc.x + sh.x; x.y = x.y * sc.y + sh.y;
      x.z = x.z * sc.z + sh.z; x.w = x.w * sc.w + sh.w;
    }
    st4[e4] = x;
  }
  __syncthreads();
  // QKV: colA = tid (q if <128, k else), all rows; colB = 256+(tid&127) (v), rows 2r+ph
  {
    const int ph = tid >> 7, cB = tid & 127;
    float a1[20], a2[10];
#pragma unroll
    for (int i = 0; i < 20; i++) a1[i] = 0.f;
#pragma unroll
    for (int r = 0; r < 10; r++) a2[r] = 0.f;
    const float4* wp = (const float4*)g_Wqkvp + l * 12288;
    for (int k4 = 0; k4 < 32; k4++) {
      float4 wA = wp[k4 * 384 + tid];
      float4 wB = wp[k4 * 384 + 256 + cB];
#pragma unroll
      for (int i = 0; i < 20; i++)
        if (i < n) a1[i] += DOT4(st4[i * 32 + k4], wA);
#pragma unroll
      for (int r = 0; r < 10; r++) {
        int i = 2 * r + ph;
        if (i < n) a2[r] += DOT4(st4[i * 32 + k4], wB);
      }
    }
    if (tid < 128) {
#pragma unroll
      for (int i = 0; i < 20; i++) if (i < n) s_q[i * 128 + tid] = a1[i];
    } else {
#pragma unroll
      for (int i = 0; i < 20; i++) if (i < n) s_kT[(tid - 128) * 20 + i] = a1[i];
    }
#pragma unroll
    for (int r = 0; r < 10; r++) {
      int i = 2 * r + ph;
      if (i < n) s_v[i * 128 + cB] = a2[r];
    }
  }
  __syncthreads();
  // attention, all 8 heads
  const int nn = n * n;
  for (int e = tid; e < 8 * nn; e += 256) {
    int hh = e / nn, rem = e % nn, i = rem / n, m = rem % n;
    float dacc = 0.f;
#pragma unroll
    for (int k2 = 0; k2 < 16; k2++)
      dacc += s_q[i * 128 + hh * 16 + k2] * s_kT[(hh * 16 + k2) * 20 + m];
    s_att[hh * 400 + i * 20 + m] = dacc * 0.25f;
  }
  __syncthreads();
  for (int r = tid; r < 8 * n; r += 256) {
    int hh = r / n, i = r % n;
    float* row = s_att + hh * 400 + i * 20;
    float mx = row[0];
    for (int m = 1; m < n; m++) mx = fmaxf(mx, row[m]);
    float s = 0.f;
    for (int m = 0; m < n; m++) { float ev = __expf(row[m] - mx); row[m] = ev; s += ev; }
    float inv = 1.f / s;
    for (int m = 0; m < n; m++) row[m] *= inv;
  }
  __syncthreads();
  // AV: write h over s_q (q fully consumed; each element written once, never read here)
  for (int e = tid; e < 8 * n * 16; e += 256) {
    int hh = e / (n * 16), rem = e % (n * 16), i = rem >> 4, k2 = rem & 15;
    const float* arow = s_att + hh * 400 + i * 20;
    float acc = 0.f;
    for (int m = 0; m < n; m++) acc += arow[m] * s_v[m * 128 + hh * 16 + k2];
    s_q[i * 128 + hh * 16 + k2] = acc;
  }
  __syncthreads();
  // out-proj + residual -> g_t, BN1 stats (h in s_q)
  {
    const int jcol = tid & 127, rhalf = tid >> 7;
    float acc[10];
#pragma unroll
    for (int r = 0; r < 10; r++) {
      int i = rhalf + 2 * r;
      acc[r] = (i < n) ? s_x[i * 128 + jcol] : 0.f;
    }
    const float4* wo4 = (const float4*)g_Wop + l * 4096 + jcol;
    const float4* sh4 = (const float4*)s_q;
    for (int c4 = 0; c4 < 32; c4++) {
      float4 w = wo4[c4 * 128];
#pragma unroll
      for (int r = 0; r < 10; r++) {
        int i = rhalf + 2 * r;
        if (i < n) acc[r] += DOT4(sh4[i * 32 + c4], w);
      }
    }
    float sm = 0.f, sq = 0.f;
#pragma unroll
    for (int r = 0; r < 10; r++) {
      int i = rhalf + 2 * r;
      if (i < n) { g_t[b * 2560 + i * 128 + jcol] = acc[r]; sm += acc[r]; sq += acc[r] * acc[r]; }
    }
    __syncthreads();
    if (rhalf == 1) { s_sm[jcol] = sm; s_sq[jcol] = sq; }
    __syncthreads();
    if (rhalf == 0) {
      float* slot = &g_bn[((step * 6 + l * 2) * 8 + (b & 7)) * 256];
      atomicAdd(&slot[jcol], sm + s_sm[jcol]);
      atomicAdd(&slot[128 + jcol], sq + s_sq[jcol]);
    }
  }
}

// KFF: fused FF over flattened rows. grid 32n blocks of 16 rows. (R7-exact)
__global__ __launch_bounds__(256) void kff(Params p, int step, int l) {
  const int tid = threadIdx.x, bx = blockIdx.x;
  const int n = 20 - step;
  const int r0 = bx * 16;
  __shared__ __align__(16) float s_x[16 * 128];
  __shared__ __align__(16) float s_hid[16 * 512];
  __shared__ __align__(16) float s_scale[128], s_shift[128];
  __shared__ float s_bn[8 * 128 * 2];

  bn_coef(step * 6 + l * 2, p.g1 + l * 128, p.b1 + l * 128, (float)(512 * n), s_scale, s_shift, tid);
  __syncthreads();
  {
    float4* sx4 = (float4*)s_x;
    for (int e4 = tid; e4 < 16 * 32; e4 += 256) {
      int row = e4 >> 5, d4 = e4 & 31;
      int r = r0 + row, b = r / n, i = r - b * n;
      float4 x = *(const float4*)(g_t + b * 2560 + i * 128 + d4 * 4);
      float4 sc = ((const float4*)s_scale)[d4];
      float4 sf = ((const float4*)s_shift)[d4];
      x.x = x.x * sc.x + sf.x; x.y = x.y * sc.y + sf.y;
      x.z = x.z * sc.z + sf.z; x.w = x.w * sc.w + sf.w;
      sx4[e4] = x;
    }
  }
  __syncthreads();
  {
    const int cg = tid & 63, rg = tid >> 6;
    float acc[4][8];
#pragma unroll
    for (int rr = 0; rr < 4; rr++)
#pragma unroll
      for (int c = 0; c < 8; c++) acc[rr][c] = 0.f;
    const float4* w1 = (const float4*)g_W1q + l * 16384 + cg;
    const float4* xx = (const float4*)s_x + rg * 4 * 32;
    for (int k4 = 0; k4 < 32; k4++) {
      float4 xr0 = xx[k4], xr1 = xx[32 + k4], xr2 = xx[64 + k4], xr3 = xx[96 + k4];
#pragma unroll
      for (int c = 0; c < 8; c++) {
        float4 w = w1[(k4 * 8 + c) * 64];
        acc[0][c] += DOT4(xr0, w); acc[1][c] += DOT4(xr1, w);
        acc[2][c] += DOT4(xr2, w); acc[3][c] += DOT4(xr3, w);
      }
    }
    float4 b1a = *(const float4*)(p.fb1 + l * FFc + cg * 8);
    float4 b1b = *(const float4*)(p.fb1 + l * FFc + cg * 8 + 4);
#pragma unroll
    for (int rr = 0; rr < 4; rr++) {
      int row = rg * 4 + rr;
      float4 u0, u1;
      u0.x = fmaxf(acc[rr][0] + b1a.x, 0.f); u0.y = fmaxf(acc[rr][1] + b1a.y, 0.f);
      u0.z = fmaxf(acc[rr][2] + b1a.z, 0.f); u0.w = fmaxf(acc[rr][3] + b1a.w, 0.f);
      u1.x = fmaxf(acc[rr][4] + b1b.x, 0.f); u1.y = fmaxf(acc[rr][5] + b1b.y, 0.f);
      u1.z = fmaxf(acc[rr][6] + b1b.z, 0.f); u1.w = fmaxf(acc[rr][7] + b1b.w, 0.f);
      *(float4*)&s_hid[row * 512 + cg * 8] = u0;
      *(float4*)&s_hid[row * 512 + cg * 8 + 4] = u1;
    }
  }
  __syncthreads();
  {
    const int cg = tid & 31, rg = tid >> 5;
    float acc0[4], acc1[4];
#pragma unroll
    for (int c = 0; c < 4; c++) { acc0[c] = 0.f; acc1[c] = 0.f; }
    const float4* w2 = (const float4*)g_W2q + l * 16384 + cg;
    const float4* hh = (const float4*)s_hid + rg * 2 * 128;
    for (int k4 = 0; k4 < 128; k4++) {
      float4 h0 = hh[k4], h1 = hh[128 + k4];
#pragma unroll
      for (int c = 0; c < 4; c++) {
        float4 w = w2[(k4 * 4 + c) * 32];
        acc0[c] += DOT4(h0, w); acc1[c] += DOT4(h1, w);
      }
    }
    float4 f2 = *(const float4*)(p.fb2 + l * 128 + cg * 4);
#pragma unroll
    for (int rr = 0; rr < 2; rr++) {
      int row = rg * 2 + rr;
      int r = r0 + row, b = r / n, i = r - b * n;
      float4 xr = ((const float4*)s_x)[row * 32 + cg];
      float4 u;
      u.x = xr.x + (rr ? acc1[0] : acc0[0]) + f2.x;
      u.y = xr.y + (rr ? acc1[1] : acc0[1]) + f2.y;
      u.z = xr.z + (rr ? acc1[2] : acc0[2]) + f2.z;
      u.w = xr.w + (rr ? acc1[3] : acc0[3]) + f2.w;
      *(float4*)(g_t + b * 2560 + i * 128 + cg * 4) = u;
      if (rr == 0) {
        s_bn[(rg * 128 + cg * 4 + 0) * 2] = u.x; s_bn[(rg * 128 + cg * 4 + 0) * 2 + 1] = u.x * u.x;
        s_bn[(rg * 128 + cg * 4 + 1) * 2] = u.y; s_bn[(rg * 128 + cg * 4 + 1) * 2 + 1] = u.y * u.y;
        s_bn[(rg * 128 + cg * 4 + 2) * 2] = u.z; s_bn[(rg * 128 + cg * 4 + 2) * 2 + 1] = u.z * u.z;
        s_bn[(rg * 128 + cg * 4 + 3) * 2] = u.w; s_bn[(rg * 128 + cg * 4 + 3) * 2 + 1] = u.w * u.w;
      } else {
        s_bn[(rg * 128 + cg * 4 + 0) * 2] += u.x; s_bn[(rg * 128 + cg * 4 + 0) * 2 + 1] += u.x * u.x;
        s_bn[(rg * 128 + cg * 4 + 1) * 2] += u.y; s_bn[(rg * 128 + cg * 4 + 1) * 2 + 1] += u.y * u.y;
        s_bn[(rg * 128 + cg * 4 + 2) * 2] += u.z; s_bn[(rg * 128 + cg * 4 + 2) * 2 + 1] += u.z * u.z;
        s_bn[(rg * 128 + cg * 4 + 3) * 2] += u.w; s_bn[(rg * 128 + cg * 4 + 3) * 2 + 1] += u.w * u.w;
      }
    }
  }
  __syncthreads();
  if (tid < 128) {
    float sm = 0.f, sq = 0.f;
#pragma unroll
    for (int rg = 0; rg < 8; rg++) { sm += s_bn[(rg * 128 + tid) * 2]; sq += s_bn[(rg * 128 + tid) * 2 + 1]; }
    float* slot = &g_bn[((step * 6 + l * 2 + 1) * 8 + (bx & 7)) * 256];
    atomicAdd(&slot[tid], sm);
    atomicAdd(&slot[128 + tid], sq);
  }
}

// KD1: grid (512, 2 = col half). (R7-exact)
__global__ __launch_bounds__(256) void kd1(Params p, int step) {
  const int tid = threadIdx.x, b = blockIdx.x, bc = blockIdx.y;
  const int n = 20 - step;
  const int cb = tid & 63, rg = tid >> 6;
  __shared__ __align__(16) float s_t[2560];
  __shared__ __align__(16) float s_scale[128], s_shift[128];
  __shared__ __align__(16) float s_gmean[128];
  __shared__ float s_red[256];

  bn_coef(step * 6 + 5, p.g2 + 2 * 128, p.b2 + 2 * 128, (float)(512 * n), s_scale, s_shift, tid);
  __syncthreads();
  const float4* src4 = (const float4*)(g_t + b * 2560);
  float4* st4 = (float4*)s_t;
  for (int e4 = tid; e4 < n * 32; e4 += 256) {
    float4 x = src4[e4];
    float4 sc = ((const float4*)s_scale)[e4 & 31];
    float4 sf = ((const float4*)s_shift)[e4 & 31];
    x.x = x.x * sc.x + sf.x; x.y = x.y * sc.y + sf.y;
    x.z = x.z * sc.z + sf.z; x.w = x.w * sc.w + sf.w;
    st4[e4] = x;
  }
  __syncthreads();
  if (tid < 128) {
    float ssum = 0.f;
    for (int i2 = 0; i2 < n; i2++) ssum += s_t[i2 * 128 + tid];
    s_gmean[tid] = ssum / (float)n;
  }
  __syncthreads();
  {
    float acc[3][5];
#pragma unroll
    for (int cc = 0; cc < 3; cc++)
#pragma unroll
      for (int r = 0; r < 5; r++) acc[cc][r] = 0.f;
    const float4* wn4 = (const float4*)g_Wnp + bc * 192 + cb;
    for (int d4 = 0; d4 < 32; d4++) {
      float4 w0 = wn4[d4 * 384], w1 = wn4[d4 * 384 + 64], w2 = wn4[d4 * 384 + 128];
#pragma unroll
      for (int r = 0; r < 5; r++) {
        int i = rg + 4 * r;
        if (i < n) {
          float4 x = st4[i * 32 + d4];
          acc[0][r] += DOT4(x, w0); acc[1][r] += DOT4(x, w1); acc[2][r] += DOT4(x, w2);
        }
      }
    }
#pragma unroll
    for (int r = 0; r < 5; r++) {
      int i = rg + 4 * r;
      if (i < n) {
#pragma unroll
        for (int cc = 0; cc < 3; cc++)
          g_dec[b * 7680 + i * 384 + bc * 192 + cb + 64 * cc] = acc[cc][r];
      }
    }
  }
  {
    int jj = bc * 256 + tid;
    float a = g_cctx[jj];
    const float4* wc4 = (const float4*)g_Wc1p + jj;
    const float4* gm4 = (const float4*)s_gmean;
    for (int e4 = 0; e4 < 32; e4++) { float4 w = wc4[e4 * 512]; float4 g = gm4[e4]; a += DOT4(g, w); }
    s_red[tid] = fmaxf(a, 0.f) * p.Wc2[jj];
  }
  __syncthreads();
#pragma unroll
  for (int sred = 128; sred > 0; sred >>= 1) {
    if (tid < sred) s_red[tid] += s_red[tid + sred];
    __syncthreads();
  }
  if (tid == 0) atomicAdd(&g_val[b], s_red[0]);
  if (bc == 0 && tid < 128) {
    float a = g_ctxq[tid];
    const float4* wf4 = (const float4*)g_Wfp + tid;
    const float4* gm4 = (const float4*)s_gmean;
    for (int e4 = 0; e4 < 32; e4++) { float4 w = wf4[e4 * 128]; float4 g = gm4[e4]; a += DOT4(g, w); }
    g_qv[b * 128 + tid] = a;
  }
}

// KD2: grid 512. (R7-exact)
__global__ __launch_bounds__(256) void kd2(Params p, int step) {
  const int tid = threadIdx.x, b = blockIdx.x;
  const int n = 20 - step;
  __shared__ __align__(16) float s_dec[7680];
  __shared__ float s_qv[128], s_glq[128];
  __shared__ __align__(16) float s_red[128];
  __shared__ float s_att[160];
  __shared__ float s_logits[20];
  __shared__ int s_sel;

  {
    const float4* src4 = (const float4*)(g_dec + b * 7680);
    float4* sd4 = (float4*)s_dec;
    for (int e4 = tid; e4 < n * 96; e4 += 256) sd4[e4] = src4[e4];
    if (tid < 128) s_qv[tid] = g_qv[b * 128 + tid];
  }
  __syncthreads();
  for (int e = tid; e < Hc * n; e += 256) {
    int hh = e / n, m = e % n;
    float dacc = 0.f;
#pragma unroll
    for (int k2 = 0; k2 < 16; k2++) dacc += s_qv[hh * 16 + k2] * s_dec[m * 384 + hh * 16 + k2];
    s_att[hh * 20 + m] = dacc * 0.25f;
  }
  __syncthreads();
  if (tid < Hc) {
    float* row = s_att + tid * 20;
    float mx = row[0];
    for (int m = 1; m < n; m++) mx = fmaxf(mx, row[m]);
    float s = 0.f;
    for (int m = 0; m < n; m++) { float ev = __expf(row[m] - mx); row[m] = ev; s += ev; }
    float inv = 1.f / s;
    for (int m = 0; m < n; m++) row[m] *= inv;
  }
  __syncthreads();
  if (tid < 128) {
    int hh = tid >> 4;
    const float* arow = s_att + hh * 20;
    float acc = 0.f;
    for (int m = 0; m < n; m++) acc += arow[m] * s_dec[m * 384 + 128 + tid];
    s_red[tid] = acc;
  }
  __syncthreads();
  if (tid < 128) {
    float a = 0.f;
    const float4* wo4 = (const float4*)g_Woup + tid;
    const float4* rr4 = (const float4*)s_red;
    for (int c4 = 0; c4 < 32; c4++) { float4 w = wo4[c4 * 128]; float4 r = rr4[c4]; a += DOT4(r, w); }
    s_glq[tid] = a;
  }
  __syncthreads();
  if (tid < n) {
    const float* lk = s_dec + tid * 384 + 256;
    float dacc = 0.f;
    for (int d = 0; d < 128; d++) dacc += s_glq[d] * lk[d];
    s_logits[tid] = 10.f * tanhf(dacc / 11.313708498984761f);
  }
  __syncthreads();
  if (tid == 0) {
    float mx = s_logits[0]; int sel = 0;
    for (int i2 = 1; i2 < n; i2++) if (s_logits[i2] > mx) { mx = s_logits[i2]; sel = i2; }
    float s = 0.f;
    for (int i2 = 0; i2 < n; i2++) s += __expf(s_logits[i2] - mx);
    p.out[b * 20 + step] = -logf(s);
    float cx = g_crd[b * 40 + 2 * sel], cy = g_crd[b * 40 + 2 * sel + 1];
    float ir = 0.f;
    if (step > 0) {
      float dx = cx - g_state[b * 8 + 0], dy = cy - g_state[b * 8 + 1];
      float dist = sqrtf(dx * dx + dy * dy);
      ir = -dist;
      g_state[b * 8 + 4] += dist;
    } else { g_state[b * 8 + 2] = cx; g_state[b * 8 + 3] = cy; g_state[b * 8 + 4] = 0.f; }
    p.out[10240 + b * 20 + step] = ir;
    p.out[31744 + b * 20 + step] = (float)g_idx[b * 20 + sel];
    g_state[b * 8 + 0] = cx; g_state[b * 8 + 1] = cy;
    if (step == 19) {
      float dx = g_state[b * 8 + 2] - cx, dy = g_state[b * 8 + 3] - cy;
      float dc = sqrtf(dx * dx + dy * dy);
      p.out[31232 + b] = -dc;
      p.out[30720 + b] = g_state[b * 8 + 4] + dc;
    }
    p.out[20480 + b * 20 + step] = g_val[b] + p.bc2[0];
    g_val[b] = 0.f;
    s_sel = sel;
  }
  __syncthreads();
  if (step < 19) {
    const int sel = s_sel;
    const int movecnt = (n - 1 - sel) * 128;
    float tmp[10]; float crdv = 0.f; int idxv = 0;
#pragma unroll
    for (int r = 0; r < 10; r++) { int e = tid + r * 256; if (e < movecnt) tmp[r] = g_x[b * 2560 + (sel + 1) * 128 + e]; }
    const int mc2 = (n - 1 - sel) * 2;
    if (tid < mc2) crdv = g_crd[b * 40 + (sel + 1) * 2 + tid];
    if (tid < n - 1 - sel) idxv = g_idx[b * 20 + sel + 1 + tid];
    __syncthreads();
#pragma unroll
    for (int r = 0; r < 10; r++) { int e = tid + r * 256; if (e < movecnt) g_x[b * 2560 + sel * 128 + e] = tmp[r]; }
    if (tid < mc2) g_crd[b * 40 + sel * 2 + tid] = crdv;
    if (tid < n - 1 - sel) g_idx[b * 20 + sel + tid] = idxv;
  }
}

extern "C" void kernel_launch(void* const* d_in, const int* in_sizes, int n_in,
                              void* d_out, int out_size, void* d_ws, size_t ws_size,
                              hipStream_t stream) {
  Params p;
  p.coords  = (const float*)d_in[0];
  p.Wi      = (const float*)d_in[1];
  p.bi      = (const float*)d_in[2];
  p.W_ph    = (const float*)d_in[3];
  p.Wq      = (const float*)d_in[4];
  p.Wk      = (const float*)d_in[5];
  p.Wv      = (const float*)d_in[6];
  p.Wo      = (const float*)d_in[7];
  p.g1      = (const float*)d_in[8];
  p.b1      = (const float*)d_in[9];
  p.fW1     = (const float*)d_in[10];
  p.fb1     = (const float*)d_in[11];
  p.fW2     = (const float*)d_in[12];
  p.fb2     = (const float*)d_in[13];
  p.g2      = (const float*)d_in[14];
  p.b2      = (const float*)d_in[15];
  p.W_node  = (const float*)d_in[16];
  p.W_fixed = (const float*)d_in[17];
  p.W_step  = (const float*)d_in[18];
  p.W_out   = (const float*)d_in[19];
  p.Wc1     = (const float*)d_in[20];
  p.bc1     = (const float*)d_in[21];
  p.Wc2     = (const float*)d_in[22];
  p.bc2     = (const float*)d_in[23];
  p.out = (float*)d_out;

  kinit<<<512, 256, 0, stream>>>(p);
  for (int step = 0; step < 20; step++) {
    const int n = 20 - step;
    for (int l = 0; l < 3; l++) {
      ka<<<512, 256, 0, stream>>>(p, step, l);
      kff<<<dim3(32 * n), 256, 0, stream>>>(p, step, l);
    }
    kd1<<<dim3(512, 2), 256, 0, stream>>>(p, step);
    kd2<<<512, 256, 0, stream>>>(p, step);
  }
}

// Round 13
// 6897.360 us; speedup vs baseline: 1.1865x; 1.1865x over previous
//
#include <hip/hip_runtime.h>
#include <cmath>

namespace {
constexpr int Hc = 8, FFc = 512, HIDc = 512;
}

struct Params {
  const float *coords, *Wi, *bi, *W_ph;
  const float *Wq, *Wk, *Wv, *Wo, *g1, *b1, *fW1, *fb1, *fW2, *fb2, *g2, *b2;
  const float *W_node, *W_fixed, *W_step, *W_out, *Wc1, *bc1, *Wc2, *bc2;
  float* out;
};

// Journal: FINAL — Round-7/11 configuration (best measured: 6.912 ms, reproduced).
// Mapped design space: R5 (4-way row split: dup weight traffic), R8 (kernel split:
// dup weights + stranded latency-bound attention), R9 (512-thr kff: 2x weight refetch),
// R10 (32-row/16n kff: grid starvation), R12 (merged ka: LDS-broadcast-pipe bound)
// ALL regressed. kff sits at the weight-traffic/parallelism saddle; ka1/ka2 keep
// per-thread row coverage at 5 rows. Structural constraint: 140 BN-forced serialized
// dispatches, each L2-weight-stream bound at >=512-block parallelism.
__device__ __align__(16) float g_bn[120 * 8 * 256]; // BN stats, 8-way replicated
__device__ __align__(16) float g_x[512 * 2560];
__device__ __align__(16) float g_t[512 * 2560];
__device__ __align__(16) float g_h[512 * 2560];
__device__ __align__(16) float g_dec[512 * 7680];   // gK|gV|lK per sample: [i<20][j<384]
__device__ __align__(16) float g_qv[512 * 128];
__device__ float g_val[512];
__device__ __align__(16) float g_crd[512 * 40];
__device__ int   g_idx[512 * 20];
__device__ float g_state[512 * 8];
__device__ __align__(16) float g_ctxq[128];
__device__ __align__(16) float g_cctx[512];
// Interleaved-packed weights: float4 at (k4*J + j) holds W[k4*4+0..3][j]
__device__ __align__(16) float g_Wqp[3 * 16384];    // [l][d4<32][j<128][4]
__device__ __align__(16) float g_Wkp[3 * 16384];
__device__ __align__(16) float g_Wvp[3 * 16384];
__device__ __align__(16) float g_Wop[3 * 16384];    // [l][c4<32][j<128][4]
// FF packs tuned for kff's read pattern (lane-consecutive per instruction):
__device__ __align__(16) float g_W1q[3 * 65536];    // [l][k4<32][c<8][cg<64][4]: col=cg*8+c
__device__ __align__(16) float g_W2q[3 * 65536];    // [l][k4<128][c<4][cg<32][4]: col=cg*4+c
__device__ __align__(16) float g_Wnp[49152];        // [e4<32][col<384][4]
__device__ __align__(16) float g_Wfp[16384];        // [e4<32][j<128][4]
__device__ __align__(16) float g_Woup[16384];       // [c4<32][j<128][4]
__device__ __align__(16) float g_Wc1p[65536];       // [e4<32][jj<512][4]

#define DOT4(a, b) ((a).x*(b).x + (a).y*(b).y + (a).z*(b).z + (a).w*(b).w)

__device__ __forceinline__ void bn_coef(int slot, const float* g, const float* bb, float cnt,
                                        float* s_scale, float* s_shift, int tid) {
  if (tid < 128) {
    float sm = 0.f, sq = 0.f;
#pragma unroll
    for (int r = 0; r < 8; r++) {
      const float* s = &g_bn[(slot * 8 + r) * 256];
      sm += s[tid]; sq += s[128 + tid];
    }
    float m_ = sm / cnt;
    float v_ = sq / cnt - m_ * m_;
    float rs = rsqrtf(v_ + 1e-5f);
    float sc = rs * g[tid];
    s_scale[tid] = sc;
    s_shift[tid] = bb[tid] - m_ * sc;
  }
}

__global__ __launch_bounds__(256) void kinit(Params p) {
  const int tid = threadIdx.x, b = blockIdx.x;
  const int gid = b * 256 + tid, GS = 512 * 256;
  for (int i = gid; i < 120 * 8 * 256; i += GS) g_bn[i] = 0.f;
  if (gid < 512) g_val[gid] = 0.f;
  for (int e = tid; e < 2560; e += 256) {
    int i = e >> 7, d = e & 127;
    float cx = p.coords[b * 40 + 2 * i], cy = p.coords[b * 40 + 2 * i + 1];
    g_x[b * 2560 + e] = cx * p.Wi[d] + cy * p.Wi[128 + d] + p.bi[d];
  }
  if (tid < 40) g_crd[b * 40 + tid] = p.coords[b * 40 + tid];
  if (tid < 20) g_idx[b * 20 + tid] = tid;
  if (tid < 8) g_state[b * 8 + tid] = 0.f;
  if (b == 0) {
    if (tid < 128) {
      float a = 0.f;
      for (int j = 0; j < 256; j++) a += p.W_ph[j] * p.W_step[j * 128 + tid];
      g_ctxq[tid] = a;
    }
    for (int jj = tid; jj < 512; jj += 256) {
      float a = p.bc1[jj];
      for (int e = 0; e < 256; e++) a += p.W_ph[e] * p.Wc1[(128 + e) * 512 + jj];
      g_cctx[jj] = a;
    }
  }
  for (int e = gid; e < 3 * 16384; e += GS) {
    int sub = e & 3, rest = e >> 2;
    int j = rest & 127, rest2 = rest >> 7, d4 = rest2 & 31, l = rest2 >> 5;
    int d = d4 * 4 + sub;
    int src = l * 16384 + (j >> 4) * 2048 + d * 16 + (j & 15);
    g_Wqp[e] = p.Wq[src]; g_Wkp[e] = p.Wk[src]; g_Wvp[e] = p.Wv[src];
    int c = d;
    g_Wop[e] = p.Wo[l * 16384 + (c >> 4) * 2048 + (c & 15) * 128 + j];
  }
  // kff packs
  for (int e = gid; e < 3 * 65536; e += GS) {
    int sub = e & 3, f = (e >> 2) & 16383, l = e >> 16;
    int cg = f & 63, c = (f >> 6) & 7, k4 = f >> 9;        // k4<32
    g_W1q[e] = p.fW1[l * 65536 + (k4 * 4 + sub) * 512 + cg * 8 + c];
  }
  for (int e = gid; e < 3 * 65536; e += GS) {
    int sub = e & 3, f = (e >> 2) & 16383, l = e >> 16;
    int cg = f & 31, c = (f >> 5) & 3, k4 = f >> 7;        // k4<128
    g_W2q[e] = p.fW2[l * 65536 + (k4 * 4 + sub) * 128 + cg * 4 + c];
  }
  for (int e = gid; e < 49152; e += GS) {
    int sub = e & 3, rest = e >> 2;
    int col = rest % 384, e4 = rest / 384;
    g_Wnp[e] = p.W_node[(e4 * 4 + sub) * 384 + col];
  }
  for (int e = gid; e < 16384; e += GS) {
    int sub = e & 3, rest = e >> 2;
    int j = rest & 127, e4 = rest >> 7;
    g_Wfp[e] = p.W_fixed[(e4 * 4 + sub) * 128 + j];
    g_Woup[e] = p.W_out[(e4 * 4 + sub) * 128 + j];
  }
  for (int e = gid; e < 65536; e += GS) {
    int sub = e & 3, rest = e >> 2;
    int jj = rest & 511, e4 = rest >> 9;
    g_Wc1p[e] = p.Wc1[(e4 * 4 + sub) * 512 + jj];
  }
}

// KA1: grid (512, 2 = head-half). [BN2(l-1) apply] -> QKV (4 heads) -> softmax -> AV -> g_h.
__global__ __launch_bounds__(256) void ka1(Params p, int step, int l) {
  const int tid = threadIdx.x, b = blockIdx.x, hb = blockIdx.y;
  const int n = 20 - step;
  const int jc = tid & 63, rg = tid >> 6;
  __shared__ __align__(16) float s_t[2560];
  __shared__ __align__(16) float s_q[1280];
  __shared__ float s_kT[1280];
  __shared__ __align__(16) float s_v[1280];
  __shared__ float s_att[1600];
  __shared__ __align__(16) float s_scale[128], s_shift[128];

  if (l > 0)
    bn_coef(step * 6 + (l - 1) * 2 + 1, p.g2 + (l - 1) * 128, p.b2 + (l - 1) * 128,
            (float)(512 * n), s_scale, s_shift, tid);
  __syncthreads();
  const float4* src4 = (const float4*)((l == 0 ? g_x : g_t) + b * 2560);
  float4* st4 = (float4*)s_t;
  for (int e4 = tid; e4 < n * 32; e4 += 256) {
    float4 x = src4[e4];
    if (l > 0) {
      float4 sc = ((const float4*)s_scale)[e4 & 31];
      float4 sh = ((const float4*)s_shift)[e4 & 31];
      x.x = x.x * sc.x + sh.x; x.y = x.y * sc.y + sh.y;
      x.z = x.z * sc.z + sh.z; x.w = x.w * sc.w + sh.w;
    }
    st4[e4] = x;
  }
  __syncthreads();
  {
    const int j = hb * 64 + jc;
    const float4* wq4 = (const float4*)g_Wqp + l * 4096 + j;
    const float4* wk4 = (const float4*)g_Wkp + l * 4096 + j;
    const float4* wv4 = (const float4*)g_Wvp + l * 4096 + j;
    float aq[5], ak[5], av[5];
#pragma unroll
    for (int r = 0; r < 5; r++) { aq[r] = 0.f; ak[r] = 0.f; av[r] = 0.f; }
    for (int d4 = 0; d4 < 32; d4++) {
      float4 wq = wq4[d4 * 128], wk = wk4[d4 * 128], wv = wv4[d4 * 128];
#pragma unroll
      for (int r = 0; r < 5; r++) {
        int i = rg + 4 * r;
        if (i < n) {
          float4 x = st4[i * 32 + d4];
          aq[r] += DOT4(x, wq); ak[r] += DOT4(x, wk); av[r] += DOT4(x, wv);
        }
      }
    }
#pragma unroll
    for (int r = 0; r < 5; r++) {
      int i = rg + 4 * r;
      if (i < n) {
        s_q[i * 64 + jc] = aq[r];
        s_kT[jc * 20 + i] = ak[r];
        s_v[i * 64 + jc] = av[r];
      }
    }
  }
  __syncthreads();
  const int nn = n * n;
  for (int e = tid; e < 4 * nn; e += 256) {
    int hl = e / nn, rem = e % nn, i = rem / n, m = rem % n;
    float dacc = 0.f;
#pragma unroll
    for (int k2 = 0; k2 < 16; k2++)
      dacc += s_q[i * 64 + hl * 16 + k2] * s_kT[(hl * 16 + k2) * 20 + m];
    s_att[hl * 400 + i * 20 + m] = dacc * 0.25f;
  }
  __syncthreads();
  for (int r = tid; r < 4 * n; r += 256) {
    int hl = r / n, i = r % n;
    float* row = s_att + hl * 400 + i * 20;
    float mx = row[0];
    for (int m = 1; m < n; m++) mx = fmaxf(mx, row[m]);
    float s = 0.f;
    for (int m = 0; m < n; m++) { float ev = __expf(row[m] - mx); row[m] = ev; s += ev; }
    float inv = 1.f / s;
    for (int m = 0; m < n; m++) row[m] *= inv;
  }
  __syncthreads();
  for (int e = tid; e < 4 * n * 16; e += 256) {
    int hl = e / (n * 16), rem = e % (n * 16), i = rem >> 4, k2 = rem & 15;
    const float* arow = s_att + hl * 400 + i * 20;
    float acc = 0.f;
    for (int m = 0; m < n; m++) acc += arow[m] * s_v[m * 64 + hl * 16 + k2];
    g_h[b * 2560 + i * 128 + hb * 64 + hl * 16 + k2] = acc;
  }
}

// KA2: grid (512, 2 = row parity). out-proj + residual -> g_t, BN1 stats.
__global__ __launch_bounds__(256) void ka2(Params p, int step, int l) {
  const int tid = threadIdx.x, b = blockIdx.x, s = blockIdx.y;
  const int n = 20 - step;
  const int jcol = tid & 127, rhalf = tid >> 7;
  __shared__ __align__(16) float s_h[2560];
  __shared__ __align__(16) float s_x[2560];
  __shared__ __align__(16) float s_scale[128], s_shift[128];
  __shared__ float s_sm[128], s_sq[128];

  if (l > 0)
    bn_coef(step * 6 + (l - 1) * 2 + 1, p.g2 + (l - 1) * 128, p.b2 + (l - 1) * 128,
            (float)(512 * n), s_scale, s_shift, tid);
  __syncthreads();
  const float4* src4 = (const float4*)((l == 0 ? g_x : g_t) + b * 2560);
  const float4* gh4 = (const float4*)(g_h + b * 2560);
  float4* sh4 = (float4*)s_h;
  float4* sx4 = (float4*)s_x;
  for (int e4 = tid; e4 < n * 32; e4 += 256) {
    int i = e4 >> 5;
    if (((i ^ s) & 1) == 0) {
      sh4[e4] = gh4[e4];
      float4 x = src4[e4];
      if (l > 0) {
        float4 sc = ((const float4*)s_scale)[e4 & 31];
        float4 sf = ((const float4*)s_shift)[e4 & 31];
        x.x = x.x * sc.x + sf.x; x.y = x.y * sc.y + sf.y;
        x.z = x.z * sc.z + sf.z; x.w = x.w * sc.w + sf.w;
      }
      sx4[e4] = x;
    }
  }
  __syncthreads();
  float acc[5];
#pragma unroll
  for (int r = 0; r < 5; r++) {
    int i = s + 2 * (rhalf + 2 * r);
    acc[r] = (i < n) ? s_x[i * 128 + jcol] : 0.f;
  }
  const float4* wo4 = (const float4*)g_Wop + l * 4096 + jcol;
  for (int c4 = 0; c4 < 32; c4++) {
    float4 w = wo4[c4 * 128];
#pragma unroll
    for (int r = 0; r < 5; r++) {
      int i = s + 2 * (rhalf + 2 * r);
      if (i < n) { float4 h = sh4[i * 32 + c4]; acc[r] += DOT4(h, w); }
    }
  }
  float sm = 0.f, sq = 0.f;
#pragma unroll
  for (int r = 0; r < 5; r++) {
    int i = s + 2 * (rhalf + 2 * r);
    if (i < n) { g_t[b * 2560 + i * 128 + jcol] = acc[r]; sm += acc[r]; sq += acc[r] * acc[r]; }
  }
  __syncthreads();
  if (rhalf == 1) { s_sm[jcol] = sm; s_sq[jcol] = sq; }
  __syncthreads();
  if (rhalf == 0) {
    float* slot = &g_bn[((step * 6 + l * 2) * 8 + ((b * 2 + s) & 7)) * 256];
    atomicAdd(&slot[jcol], sm + s_sm[jcol]);
    atomicAdd(&slot[128 + jcol], sq + s_sq[jcol]);
  }
}

// KFF: fused FF over flattened rows. grid 32n blocks of 16 rows.
// BN1 apply (staging) -> hidden (LDS) -> FF2 -> +residual+fb2 -> g_t, BN2 stats.
__global__ __launch_bounds__(256) void kff(Params p, int step, int l) {
  const int tid = threadIdx.x, bx = blockIdx.x;
  const int n = 20 - step;
  const int r0 = bx * 16;
  __shared__ __align__(16) float s_x[16 * 128];     // BN1-applied X tile
  __shared__ __align__(16) float s_hid[16 * 512];   // hidden
  __shared__ __align__(16) float s_scale[128], s_shift[128];
  __shared__ float s_bn[8 * 128 * 2];               // [rg][col][sm|sq]

  bn_coef(step * 6 + l * 2, p.g1 + l * 128, p.b1 + l * 128, (float)(512 * n), s_scale, s_shift, tid);
  __syncthreads();
  {
    float4* sx4 = (float4*)s_x;
    for (int e4 = tid; e4 < 16 * 32; e4 += 256) {
      int row = e4 >> 5, d4 = e4 & 31;
      int r = r0 + row, b = r / n, i = r - b * n;
      float4 x = *(const float4*)(g_t + b * 2560 + i * 128 + d4 * 4);
      float4 sc = ((const float4*)s_scale)[d4];
      float4 sf = ((const float4*)s_shift)[d4];
      x.x = x.x * sc.x + sf.x; x.y = x.y * sc.y + sf.y;
      x.z = x.z * sc.z + sf.z; x.w = x.w * sc.w + sf.w;
      sx4[e4] = x;
    }
  }
  __syncthreads();
  // stage 1: hidden = relu(X @ W1 + fb1). thread: cg=tid&63 (cols cg*8..+7), rg=tid>>6 (rows rg*4..+3)
  {
    const int cg = tid & 63, rg = tid >> 6;
    float acc[4][8];
#pragma unroll
    for (int rr = 0; rr < 4; rr++)
#pragma unroll
      for (int c = 0; c < 8; c++) acc[rr][c] = 0.f;
    const float4* w1 = (const float4*)g_W1q + l * 16384 + cg;
    const float4* xx = (const float4*)s_x + rg * 4 * 32;
    for (int k4 = 0; k4 < 32; k4++) {
      float4 xr0 = xx[k4], xr1 = xx[32 + k4], xr2 = xx[64 + k4], xr3 = xx[96 + k4];
#pragma unroll
      for (int c = 0; c < 8; c++) {
        float4 w = w1[(k4 * 8 + c) * 64];
        acc[0][c] += DOT4(xr0, w); acc[1][c] += DOT4(xr1, w);
        acc[2][c] += DOT4(xr2, w); acc[3][c] += DOT4(xr3, w);
      }
    }
    float4 b1a = *(const float4*)(p.fb1 + l * FFc + cg * 8);
    float4 b1b = *(const float4*)(p.fb1 + l * FFc + cg * 8 + 4);
#pragma unroll
    for (int rr = 0; rr < 4; rr++) {
      int row = rg * 4 + rr;
      float4 u0, u1;
      u0.x = fmaxf(acc[rr][0] + b1a.x, 0.f); u0.y = fmaxf(acc[rr][1] + b1a.y, 0.f);
      u0.z = fmaxf(acc[rr][2] + b1a.z, 0.f); u0.w = fmaxf(acc[rr][3] + b1a.w, 0.f);
      u1.x = fmaxf(acc[rr][4] + b1b.x, 0.f); u1.y = fmaxf(acc[rr][5] + b1b.y, 0.f);
      u1.z = fmaxf(acc[rr][6] + b1b.z, 0.f); u1.w = fmaxf(acc[rr][7] + b1b.w, 0.f);
      *(float4*)&s_hid[row * 512 + cg * 8] = u0;
      *(float4*)&s_hid[row * 512 + cg * 8 + 4] = u1;
    }
  }
  __syncthreads();
  // stage 2: out = hid @ W2 + Xbn + fb2. thread: cg=tid&31 (cols cg*4..+3), rg=tid>>5 (rows rg*2..+1)
  {
    const int cg = tid & 31, rg = tid >> 5;
    float acc0[4], acc1[4];
#pragma unroll
    for (int c = 0; c < 4; c++) { acc0[c] = 0.f; acc1[c] = 0.f; }
    const float4* w2 = (const float4*)g_W2q + l * 16384 + cg;
    const float4* hh = (const float4*)s_hid + rg * 2 * 128;
    for (int k4 = 0; k4 < 128; k4++) {
      float4 h0 = hh[k4], h1 = hh[128 + k4];
#pragma unroll
      for (int c = 0; c < 4; c++) {
        float4 w = w2[(k4 * 4 + c) * 32];
        acc0[c] += DOT4(h0, w); acc1[c] += DOT4(h1, w);
      }
    }
    float4 f2 = *(const float4*)(p.fb2 + l * 128 + cg * 4);
#pragma unroll
    for (int rr = 0; rr < 2; rr++) {
      int row = rg * 2 + rr;
      int r = r0 + row, b = r / n, i = r - b * n;
      float4 xr = ((const float4*)s_x)[row * 32 + cg];
      float4 u;
      u.x = xr.x + (rr ? acc1[0] : acc0[0]) + f2.x;
      u.y = xr.y + (rr ? acc1[1] : acc0[1]) + f2.y;
      u.z = xr.z + (rr ? acc1[2] : acc0[2]) + f2.z;
      u.w = xr.w + (rr ? acc1[3] : acc0[3]) + f2.w;
      *(float4*)(g_t + b * 2560 + i * 128 + cg * 4) = u;
      if (rr == 0) {
        s_bn[(rg * 128 + cg * 4 + 0) * 2] = u.x; s_bn[(rg * 128 + cg * 4 + 0) * 2 + 1] = u.x * u.x;
        s_bn[(rg * 128 + cg * 4 + 1) * 2] = u.y; s_bn[(rg * 128 + cg * 4 + 1) * 2 + 1] = u.y * u.y;
        s_bn[(rg * 128 + cg * 4 + 2) * 2] = u.z; s_bn[(rg * 128 + cg * 4 + 2) * 2 + 1] = u.z * u.z;
        s_bn[(rg * 128 + cg * 4 + 3) * 2] = u.w; s_bn[(rg * 128 + cg * 4 + 3) * 2 + 1] = u.w * u.w;
      } else {
        s_bn[(rg * 128 + cg * 4 + 0) * 2] += u.x; s_bn[(rg * 128 + cg * 4 + 0) * 2 + 1] += u.x * u.x;
        s_bn[(rg * 128 + cg * 4 + 1) * 2] += u.y; s_bn[(rg * 128 + cg * 4 + 1) * 2 + 1] += u.y * u.y;
        s_bn[(rg * 128 + cg * 4 + 2) * 2] += u.z; s_bn[(rg * 128 + cg * 4 + 2) * 2 + 1] += u.z * u.z;
        s_bn[(rg * 128 + cg * 4 + 3) * 2] += u.w; s_bn[(rg * 128 + cg * 4 + 3) * 2 + 1] += u.w * u.w;
      }
    }
  }
  __syncthreads();
  if (tid < 128) {
    float sm = 0.f, sq = 0.f;
#pragma unroll
    for (int rg = 0; rg < 8; rg++) { sm += s_bn[(rg * 128 + tid) * 2]; sq += s_bn[(rg * 128 + tid) * 2 + 1]; }
    float* slot = &g_bn[((step * 6 + l * 2 + 1) * 8 + (bx & 7)) * 256];
    atomicAdd(&slot[tid], sm);
    atomicAdd(&slot[128 + tid], sq);
  }
}

// KD1: grid (512, 2 = col half). BN2(l=2) apply -> W_node col-slice -> g_dec;
// gmean; critic h-slice -> atomicAdd g_val; (bc=0) query q -> g_qv.
__global__ __launch_bounds__(256) void kd1(Params p, int step) {
  const int tid = threadIdx.x, b = blockIdx.x, bc = blockIdx.y;
  const int n = 20 - step;
  const int cb = tid & 63, rg = tid >> 6;
  __shared__ __align__(16) float s_t[2560];
  __shared__ __align__(16) float s_scale[128], s_shift[128];
  __shared__ __align__(16) float s_gmean[128];
  __shared__ float s_red[256];

  bn_coef(step * 6 + 5, p.g2 + 2 * 128, p.b2 + 2 * 128, (float)(512 * n), s_scale, s_shift, tid);
  __syncthreads();
  const float4* src4 = (const float4*)(g_t + b * 2560);
  float4* st4 = (float4*)s_t;
  for (int e4 = tid; e4 < n * 32; e4 += 256) {
    float4 x = src4[e4];
    float4 sc = ((const float4*)s_scale)[e4 & 31];
    float4 sf = ((const float4*)s_shift)[e4 & 31];
    x.x = x.x * sc.x + sf.x; x.y = x.y * sc.y + sf.y;
    x.z = x.z * sc.z + sf.z; x.w = x.w * sc.w + sf.w;
    st4[e4] = x;
  }
  __syncthreads();
  if (tid < 128) {
    float ssum = 0.f;
    for (int i2 = 0; i2 < n; i2++) ssum += s_t[i2 * 128 + tid];
    s_gmean[tid] = ssum / (float)n;
  }
  __syncthreads();
  {
    float acc[3][5];
#pragma unroll
    for (int cc = 0; cc < 3; cc++)
#pragma unroll
      for (int r = 0; r < 5; r++) acc[cc][r] = 0.f;
    const float4* wn4 = (const float4*)g_Wnp + bc * 192 + cb;
    for (int d4 = 0; d4 < 32; d4++) {
      float4 w0 = wn4[d4 * 384], w1 = wn4[d4 * 384 + 64], w2 = wn4[d4 * 384 + 128];
#pragma unroll
      for (int r = 0; r < 5; r++) {
        int i = rg + 4 * r;
        if (i < n) {
          float4 x = st4[i * 32 + d4];
          acc[0][r] += DOT4(x, w0); acc[1][r] += DOT4(x, w1); acc[2][r] += DOT4(x, w2);
        }
      }
    }
#pragma unroll
    for (int r = 0; r < 5; r++) {
      int i = rg + 4 * r;
      if (i < n) {
#pragma unroll
        for (int cc = 0; cc < 3; cc++)
          g_dec[b * 7680 + i * 384 + bc * 192 + cb + 64 * cc] = acc[cc][r];
      }
    }
  }
  {
    int jj = bc * 256 + tid;
    float a = g_cctx[jj];
    const float4* wc4 = (const float4*)g_Wc1p + jj;
    const float4* gm4 = (const float4*)s_gmean;
    for (int e4 = 0; e4 < 32; e4++) { float4 w = wc4[e4 * 512]; float4 g = gm4[e4]; a += DOT4(g, w); }
    s_red[tid] = fmaxf(a, 0.f) * p.Wc2[jj];
  }
  __syncthreads();
#pragma unroll
  for (int sred = 128; sred > 0; sred >>= 1) {
    if (tid < sred) s_red[tid] += s_red[tid + sred];
    __syncthreads();
  }
  if (tid == 0) atomicAdd(&g_val[b], s_red[0]);
  if (bc == 0 && tid < 128) {
    float a = g_ctxq[tid];
    const float4* wf4 = (const float4*)g_Wfp + tid;
    const float4* gm4 = (const float4*)s_gmean;
    for (int e4 = 0; e4 < 32; e4++) { float4 w = wf4[e4 * 128]; float4 g = gm4[e4]; a += DOT4(g, w); }
    g_qv[b * 128 + tid] = a;
  }
}

// KD2: grid 512. glimpse attention -> logits -> argmax/outputs -> compaction.
__global__ __launch_bounds__(256) void kd2(Params p, int step) {
  const int tid = threadIdx.x, b = blockIdx.x;
  const int n = 20 - step;
  __shared__ __align__(16) float s_dec[7680];
  __shared__ float s_qv[128], s_glq[128];
  __shared__ __align__(16) float s_red[128];
  __shared__ float s_att[160];
  __shared__ float s_logits[20];
  __shared__ int s_sel;

  {
    const float4* src4 = (const float4*)(g_dec + b * 7680);
    float4* sd4 = (float4*)s_dec;
    for (int e4 = tid; e4 < n * 96; e4 += 256) sd4[e4] = src4[e4];
    if (tid < 128) s_qv[tid] = g_qv[b * 128 + tid];
  }
  __syncthreads();
  for (int e = tid; e < Hc * n; e += 256) {
    int hh = e / n, m = e % n;
    float dacc = 0.f;
#pragma unroll
    for (int k2 = 0; k2 < 16; k2++) dacc += s_qv[hh * 16 + k2] * s_dec[m * 384 + hh * 16 + k2];
    s_att[hh * 20 + m] = dacc * 0.25f;
  }
  __syncthreads();
  if (tid < Hc) {
    float* row = s_att + tid * 20;
    float mx = row[0];
    for (int m = 1; m < n; m++) mx = fmaxf(mx, row[m]);
    float s = 0.f;
    for (int m = 0; m < n; m++) { float ev = __expf(row[m] - mx); row[m] = ev; s += ev; }
    float inv = 1.f / s;
    for (int m = 0; m < n; m++) row[m] *= inv;
  }
  __syncthreads();
  if (tid < 128) {
    int hh = tid >> 4;
    const float* arow = s_att + hh * 20;
    float acc = 0.f;
    for (int m = 0; m < n; m++) acc += arow[m] * s_dec[m * 384 + 128 + tid];
    s_red[tid] = acc;
  }
  __syncthreads();
  if (tid < 128) {
    float a = 0.f;
    const float4* wo4 = (const float4*)g_Woup + tid;
    const float4* rr4 = (const float4*)s_red;
    for (int c4 = 0; c4 < 32; c4++) { float4 w = wo4[c4 * 128]; float4 r = rr4[c4]; a += DOT4(r, w); }
    s_glq[tid] = a;
  }
  __syncthreads();
  if (tid < n) {
    const float* lk = s_dec + tid * 384 + 256;
    float dacc = 0.f;
    for (int d = 0; d < 128; d++) dacc += s_glq[d] * lk[d];
    s_logits[tid] = 10.f * tanhf(dacc / 11.313708498984761f);
  }
  __syncthreads();
  if (tid == 0) {
    float mx = s_logits[0]; int sel = 0;
    for (int i2 = 1; i2 < n; i2++) if (s_logits[i2] > mx) { mx = s_logits[i2]; sel = i2; }
    float s = 0.f;
    for (int i2 = 0; i2 < n; i2++) s += __expf(s_logits[i2] - mx);
    p.out[b * 20 + step] = -logf(s);
    float cx = g_crd[b * 40 + 2 * sel], cy = g_crd[b * 40 + 2 * sel + 1];
    float ir = 0.f;
    if (step > 0) {
      float dx = cx - g_state[b * 8 + 0], dy = cy - g_state[b * 8 + 1];
      float dist = sqrtf(dx * dx + dy * dy);
      ir = -dist;
      g_state[b * 8 + 4] += dist;
    } else { g_state[b * 8 + 2] = cx; g_state[b * 8 + 3] = cy; g_state[b * 8 + 4] = 0.f; }
    p.out[10240 + b * 20 + step] = ir;
    p.out[31744 + b * 20 + step] = (float)g_idx[b * 20 + sel];
    g_state[b * 8 + 0] = cx; g_state[b * 8 + 1] = cy;
    if (step == 19) {
      float dx = g_state[b * 8 + 2] - cx, dy = g_state[b * 8 + 3] - cy;
      float dc = sqrtf(dx * dx + dy * dy);
      p.out[31232 + b] = -dc;
      p.out[30720 + b] = g_state[b * 8 + 4] + dc;
    }
    p.out[20480 + b * 20 + step] = g_val[b] + p.bc2[0];
    g_val[b] = 0.f;
    s_sel = sel;
  }
  __syncthreads();
  if (step < 19) {
    const int sel = s_sel;
    const int movecnt = (n - 1 - sel) * 128;
    float tmp[10]; float crdv = 0.f; int idxv = 0;
#pragma unroll
    for (int r = 0; r < 10; r++) { int e = tid + r * 256; if (e < movecnt) tmp[r] = g_x[b * 2560 + (sel + 1) * 128 + e]; }
    const int mc2 = (n - 1 - sel) * 2;
    if (tid < mc2) crdv = g_crd[b * 40 + (sel + 1) * 2 + tid];
    if (tid < n - 1 - sel) idxv = g_idx[b * 20 + sel + 1 + tid];
    __syncthreads();
#pragma unroll
    for (int r = 0; r < 10; r++) { int e = tid + r * 256; if (e < movecnt) g_x[b * 2560 + sel * 128 + e] = tmp[r]; }
    if (tid < mc2) g_crd[b * 40 + sel * 2 + tid] = crdv;
    if (tid < n - 1 - sel) g_idx[b * 20 + sel + tid] = idxv;
  }
}

extern "C" void kernel_launch(void* const* d_in, const int* in_sizes, int n_in,
                              void* d_out, int out_size, void* d_ws, size_t ws_size,
                              hipStream_t stream) {
  Params p;
  p.coords  = (const float*)d_in[0];
  p.Wi      = (const float*)d_in[1];
  p.bi      = (const float*)d_in[2];
  p.W_ph    = (const float*)d_in[3];
  p.Wq      = (const float*)d_in[4];
  p.Wk      = (const float*)d_in[5];
  p.Wv      = (const float*)d_in[6];
  p.Wo      = (const float*)d_in[7];
  p.g1      = (const float*)d_in[8];
  p.b1      = (const float*)d_in[9];
  p.fW1     = (const float*)d_in[10];
  p.fb1     = (const float*)d_in[11];
  p.fW2     = (const float*)d_in[12];
  p.fb2     = (const float*)d_in[13];
  p.g2      = (const float*)d_in[14];
  p.b2      = (const float*)d_in[15];
  p.W_node  = (const float*)d_in[16];
  p.W_fixed = (const float*)d_in[17];
  p.W_step  = (const float*)d_in[18];
  p.W_out   = (const float*)d_in[19];
  p.Wc1     = (const float*)d_in[20];
  p.bc1     = (const float*)d_in[21];
  p.Wc2     = (const float*)d_in[22];
  p.bc2     = (const float*)d_in[23];
  p.out = (float*)d_out;

  kinit<<<512, 256, 0, stream>>>(p);
  for (int step = 0; step < 20; step++) {
    const int n = 20 - step;
    for (int l = 0; l < 3; l++) {
      ka1<<<dim3(512, 2), 256, 0, stream>>>(p, step, l);
      ka2<<<dim3(512, 2), 256, 0, stream>>>(p, step, l);
      kff<<<dim3(32 * n), 256, 0, stream>>>(p, step, l);
    }
    kd1<<<dim3(512, 2), 256, 0, stream>>>(p, step);
    kd2<<<512, 256, 0, stream>>>(p, step);
  }
}